// Round 14
// baseline (1075.539 us; speedup 1.0000x reference)
//
#include <hip/hip_runtime.h>

// SingleSiteMinimizer, fp16-MFMA pipeline:
//   G1: T1[k][(L,w)][(p,r)] = envL_k @ A            } merged dual-grid dispatch
//   G3: Y'[(L,P)][k*4096+(v,r)] = A @ envR_k^T      } (blockIdx.z)
//   G4: out += sum_k sum_{m,n} (T1_k Y'_k^T)[m,n] * W2pref[k][n][m]  (fused trace)
//   out /= sum(A^2)
// Round 14: consolidation at the measured plateau. GEMM = r12 mega (best, 89us,
// 0 conflicts) with uniform vmcnt(8); g4w = r12 (proven). Prep fused: one-pass
// A -> {Ah, Ath, sumsq}; one dispatch for envL-cast + envR-transpose (z-decode).

typedef __attribute__((ext_vector_type(8))) _Float16 f16x8;
typedef __attribute__((ext_vector_type(4))) float f32x4;

#define RPS 280  // repack LDS row stride in shorts (140 dw: rows {0,4,8,12} -> 2-way)

__device__ __forceinline__ unsigned short f2h(float f) {
    _Float16 h = (_Float16)f;
    return *(unsigned short*)&h;
}

__device__ __forceinline__ void gload16(const void* g, void* l) {
    __builtin_amdgcn_global_load_lds(
        (const __attribute__((address_space(1))) void*)g,
        (__attribute__((address_space(3))) void*)l, 16, 0, 0);
}

struct GArg {
    const unsigned short* A;
    const unsigned short* B;
    unsigned short* C;
    int kshift;        // A row slab shift (30 => none)
    long long kextra;  // extra elems per slab
};

// Stage one 256x64 fp16 K-tile of A and B into linear LDS with inverse-swizzled
// global source: LDS slot (r, s) holds global k-chunk s^(r&7)  [rule 21].
__device__ __forceinline__ void stage_tile(
    const GArg& g, int srow0, int col0, int kt0,
    short* dstA, short* dstB, int tid)
{
    #pragma unroll
    for (int q = 0; q < 4; ++q) {
        const int c = q * 512 + tid;
        const int r = c >> 3;
        const int gs = (c & 7) ^ (r & 7);
        const int gr = srow0 + r;
        const size_t aoff = (size_t)gr * 512 + (size_t)((unsigned)gr >> g.kshift) * g.kextra;
        gload16(g.A + aoff + kt0 + gs * 8, dstA + c * 8);
        gload16(g.B + (size_t)(col0 + r) * 512 + kt0 + gs * 8, dstB + c * 8);
    }
}

// ---------- mega dual fp16 GEMM: C[M,N] = Aop[M,K] x Bop[N,K]^T ----------
// K=512. lda=ldb=512, ldc=16384. grid (64, 2, 2); NPB 256-row panels per block.
__global__ __launch_bounds__(512, 1) void gemm_dual_mega(int K, int NPB, GArg g0, GArg g1)
{
    __shared__ short lds[74496];  // 128KB staging (A0,B0,A1,B1) + 17.5KB repack
    const GArg g = blockIdx.z ? g1 : g0;
    const int tid = threadIdx.x;
    const int wid = tid >> 6, lane = tid & 63;
    const int wm = wid >> 2, wn = wid & 3;          // 2M x 4N waves
    const int lrow = lane & 15, lgrp = lane >> 4;
    const int sx = lrow & 7;                        // read-side swizzle xor
    const int gsw0 = (lgrp ^ sx) * 8, gsw1 = ((lgrp + 4) ^ sx) * 8;

    // XCD pin: hw linear id % 8 == blockIdx.x % 8 for this grid shape
    const int xcd = blockIdx.x & 7, loc = blockIdx.x >> 3;
    const int col0 = (xcd * 8 + loc) * 256;
    const int row_base = blockIdx.y * NPB * 256;

    short* A0 = lds;          short* B0 = lds + 16384;
    short* A1 = lds + 32768;  short* B1 = lds + 49152;
    short* repk = lds + 65536;                       // 32 x RPS shorts

    const int NT = (K >> 6) * NPB;                   // flat iterations

    f32x4 acc[8][4] = {};

    // prologue: stage it=0,1
    stage_tile(g, row_base, col0, 0, A0, B0, tid);
    stage_tile(g, row_base, col0, 64, A1, B1, tid);
    asm volatile("s_waitcnt vmcnt(8)" ::: "memory");
    __builtin_amdgcn_s_barrier();
    __builtin_amdgcn_sched_barrier(0);

    for (int it = 0; it < NT; ++it) {
        const short* cA = (it & 1) ? A1 : A0;
        const short* cB = (it & 1) ? B1 : B0;
        short* wA = (it & 1) ? A1 : A0;
        short* wB = (it & 1) ? B1 : B0;

        f16x8 bfr[4][2], afr[4][2];
        #pragma unroll
        for (int j = 0; j < 4; ++j) {
            const int R = wn * 64 + j * 16 + lrow;
            bfr[j][0] = *(const f16x8*)&cB[R * 64 + gsw0];
            bfr[j][1] = *(const f16x8*)&cB[R * 64 + gsw1];
        }
        #pragma unroll
        for (int i = 0; i < 4; ++i) {
            const int R = wm * 128 + i * 16 + lrow;
            afr[i][0] = *(const f16x8*)&cA[R * 64 + gsw0];
            afr[i][1] = *(const f16x8*)&cA[R * 64 + gsw1];
        }
        __builtin_amdgcn_s_setprio(1);
        #pragma unroll
        for (int i = 0; i < 4; ++i)
            #pragma unroll
            for (int j = 0; j < 4; ++j) {
                acc[i][j] = __builtin_amdgcn_mfma_f32_16x16x32_f16(afr[i][0], bfr[j][0], acc[i][j], 0, 0, 0);
                acc[i][j] = __builtin_amdgcn_mfma_f32_16x16x32_f16(afr[i][1], bfr[j][1], acc[i][j], 0, 0, 0);
            }
        __builtin_amdgcn_s_setprio(0);
        // phase-2 A fragments (rows 64..127 of the wave's M-half)
        #pragma unroll
        for (int i = 0; i < 4; ++i) {
            const int R = wm * 128 + (i + 4) * 16 + lrow;
            afr[i][0] = *(const f16x8*)&cA[R * 64 + gsw0];
            afr[i][1] = *(const f16x8*)&cA[R * 64 + gsw1];
        }
        asm volatile("s_waitcnt lgkmcnt(0)" ::: "memory");
        __builtin_amdgcn_sched_barrier(0);
        __builtin_amdgcn_s_barrier();               // all reads of buf[it&1] retired
        __builtin_amdgcn_sched_barrier(0);
        if (it + 2 < NT) {
            const int it2 = it + 2;
            stage_tile(g, row_base + (it2 >> 3) * 256, col0, (it2 & 7) * 64, wA, wB, tid);
        }
        __builtin_amdgcn_s_setprio(1);
        #pragma unroll
        for (int i = 0; i < 4; ++i)
            #pragma unroll
            for (int j = 0; j < 4; ++j) {
                acc[i + 4][j] = __builtin_amdgcn_mfma_f32_16x16x32_f16(afr[i][0], bfr[j][0], acc[i + 4][j], 0, 0, 0);
                acc[i + 4][j] = __builtin_amdgcn_mfma_f32_16x16x32_f16(afr[i][1], bfr[j][1], acc[i + 4][j], 0, 0, 0);
            }
        __builtin_amdgcn_s_setprio(0);
        __builtin_amdgcn_sched_barrier(0);
        if (it + 2 < NT) asm volatile("s_waitcnt vmcnt(8)" ::: "memory");  // it+1 landed
        else             asm volatile("s_waitcnt vmcnt(0)" ::: "memory");  // tail drain
        __builtin_amdgcn_sched_barrier(0);
        __builtin_amdgcn_s_barrier();
        __builtin_amdgcn_sched_barrier(0);

        // ---- panel boundary: write this panel's C, reset acc. Raw barriers only
        // (no __syncthreads: must not drain the in-flight cross-panel prefetch).
        if ((it & 7) == 7) {
            const int row0 = row_base + (it >> 3) * 256;
            const int orow = lgrp * 4, ocol = lrow;
            #pragma unroll
            for (int c8 = 0; c8 < 8; ++c8) {        // 32-row chunks
                if (wm == (c8 >> 2)) {
                    const int ib = (c8 & 3) * 2;
                    #pragma unroll
                    for (int di = 0; di < 2; ++di)
                        #pragma unroll
                        for (int j = 0; j < 4; ++j)
                            #pragma unroll
                            for (int q = 0; q < 4; ++q)
                                repk[(di * 16 + orow + q) * RPS + wn * 64 + j * 16 + ocol] =
                                    (short)f2h(acc[ib + di][j][q]);
                }
                asm volatile("s_waitcnt lgkmcnt(0)" ::: "memory");
                __builtin_amdgcn_s_barrier();
                #pragma unroll
                for (int s2 = 0; s2 < 2; ++s2) {
                    const int idx = s2 * 512 + tid;
                    const int rr = idx >> 5, cc = idx & 31;
                    *(int4*)(g.C + (size_t)(row0 + c8 * 32 + rr) * 16384 + col0 + cc * 8) =
                        *(const int4*)&repk[rr * RPS + cc * 8];
                }
                asm volatile("s_waitcnt lgkmcnt(0)" ::: "memory");
                __builtin_amdgcn_s_barrier();
            }
            #pragma unroll
            for (int i = 0; i < 8; ++i)
                #pragma unroll
                for (int j = 0; j < 4; ++j)
                    acc[i][j] = (f32x4){0.f, 0.f, 0.f, 0.f};
        }
    }
}

// ---------- G4: 512-thr, 8 waves 2Mx4N (128x64/wave), full 256x256 per block ----------
__global__ __launch_bounds__(512, 1) void gemm_g4w(
    const unsigned short* __restrict__ T1, const unsigned short* __restrict__ Yp,
    const float* __restrict__ W2p, float* __restrict__ dacc,
    int Lt8, int zkShift, int BKC)
{
    __shared__ short sh[16384];  // A = sh[0:8192] [256][32], B = sh[8192:16384]
    const int tid = threadIdx.x;
    const int wid = tid >> 6, lane = tid & 63;
    const int kidx = blockIdx.x >> zkShift;
    const int kz = (blockIdx.x - (kidx << zkShift)) * BKC;
    const int wm = wid >> 2, wn = wid & 3;          // 2M x 4N waves
    const int lrow = lane & 15, lgrp = lane >> 4;
    const int rdoff = lrow * 32 + ((lgrp ^ ((lrow >> 1) & 3)) * 8);

    const size_t T1k = (size_t)kidx * Lt8 * 16384;
    const size_t Yk = (size_t)kidx * 4096;

    f32x4 acc[8][4] = {};

    for (int k0 = 0; k0 < BKC; k0 += 32) {
        const int kk = kz + k0;
        const int lt = kk >> 9, rbase = kk & 511;
        #pragma unroll
        for (int q = 0; q < 2; ++q) {
            const int c = q * 512 + tid;
            const int row = c >> 2;
            const int gs = (c & 3) ^ ((row >> 1) & 3);
            const int hi = row >> 5, lo = row & 31;
            gload16(T1 + T1k + (size_t)(lt * 8 + hi) * 16384 + lo * 512 + rbase + gs * 8,
                    sh + c * 8);
            gload16(Yp + Yk + (size_t)(lt * 32 + lo) * 16384 + hi * 512 + rbase + gs * 8,
                    sh + 8192 + c * 8);
        }
        __syncthreads();
        f16x8 a[8], b[4];
        #pragma unroll
        for (int j = 0; j < 4; ++j)
            b[j] = *(const f16x8*)&sh[8192 + (wn * 64 + j * 16) * 32 + rdoff];
        #pragma unroll
        for (int i = 0; i < 8; ++i)
            a[i] = *(const f16x8*)&sh[(wm * 128 + i * 16) * 32 + rdoff];
        #pragma unroll
        for (int i = 0; i < 8; ++i)
            #pragma unroll
            for (int j = 0; j < 4; ++j)
                acc[i][j] = __builtin_amdgcn_mfma_f32_16x16x32_f16(a[i], b[j], acc[i][j], 0, 0, 0);
        __syncthreads();
    }

    // fused weighted trace: s = sum acc[i][j][q] * Wk[n*256 + m]
    const int orow = lgrp * 4, ocol = lrow;
    const float* Wk = W2p + ((size_t)kidx << 16);
    float s = 0.f;
    #pragma unroll
    for (int j = 0; j < 4; ++j) {
        const int n = wn * 64 + j * 16 + ocol;
        const float* wrow = Wk + (size_t)n * 256 + wm * 128 + orow;
        #pragma unroll
        for (int i = 0; i < 8; ++i) {
            float4 wv = *(const float4*)(wrow + i * 16);
            s += wv.x * acc[i][j][0] + wv.y * acc[i][j][1]
               + wv.z * acc[i][j][2] + wv.w * acc[i][j][3];
        }
    }
    __syncthreads();
    float* red = (float*)sh;
    red[tid] = s;
    __syncthreads();
    for (int st = 256; st > 0; st >>= 1) {
        if (tid < st) red[tid] += red[tid + st];
        __syncthreads();
    }
    if (tid == 0) atomicAdd(dacc, red[0]);
}

// ---------- fused A-prep: one pass -> Ah (cast), Ath (transpose-cast), sumsq ----------
// A viewed [512 rows l][16384 cols (p,r)]. grid (512, 16), block (32, 8).
__global__ void a_prep(const float* __restrict__ in, unsigned short* __restrict__ Ah,
                       unsigned short* __restrict__ Ath, float* __restrict__ sumsq)
{
    __shared__ float tile[32][33];
    const int c0 = blockIdx.x * 32, r0 = blockIdx.y * 32;
    const int tx = threadIdx.x, ty = threadIdx.y;
    float p = 0.f;
    #pragma unroll
    for (int i = 0; i < 4; ++i) {
        const float v = in[(size_t)(r0 + ty + i * 8) * 16384 + c0 + tx];
        tile[ty + i * 8][tx] = v;
        p += v * v;
        Ah[(size_t)(r0 + ty + i * 8) * 16384 + c0 + tx] = f2h(v);
    }
    __syncthreads();
    #pragma unroll
    for (int i = 0; i < 4; ++i)
        Ath[(size_t)(c0 + ty + i * 8) * 512 + r0 + tx] = f2h(tile[tx][ty + i * 8]);
    // block-reduce sumsq
    __shared__ float sh[256];
    sh[ty * 32 + tx] = p;
    __syncthreads();
    const int tid = ty * 32 + tx;
    for (int s = 128; s > 0; s >>= 1) {
        if (tid < s) sh[tid] += sh[tid + s];
        __syncthreads();
    }
    if (tid == 0) atomicAdd(sumsq, sh[0]);
}

// ---------- fused env-prep: z<4 -> envR_z transpose-cast; z>=4 -> envL_{z-4} cast ----
// grid (128, 16, 8), block (32, 8).
__global__ void env_prep(const float* __restrict__ envL, const float* __restrict__ envR,
                         unsigned short* __restrict__ envLh, unsigned short* __restrict__ envRth)
{
    const int z = blockIdx.z;
    const int tx = threadIdx.x, ty = threadIdx.y;
    if (z < 4) {
        // transpose-cast envR[z] viewed [512 R][4096 (v,r)] -> envRth[z] [4096][512]
        __shared__ float tile[32][33];
        const float* in = envR + (size_t)z * 2097152;
        unsigned short* out = envRth + (size_t)z * 2097152;
        const int c0 = blockIdx.x * 32, r0 = blockIdx.y * 32;
        #pragma unroll
        for (int i = 0; i < 4; ++i)
            tile[ty + i * 8][tx] = in[(size_t)(r0 + ty + i * 8) * 4096 + c0 + tx];
        __syncthreads();
        #pragma unroll
        for (int i = 0; i < 4; ++i)
            out[(size_t)(c0 + ty + i * 8) * 512 + r0 + tx] = f2h(tile[tx][ty + i * 8]);
    } else {
        // straight cast of envL[z-4] (2097152 floats = 524288 float4)
        const int k = z - 4;
        const float4* in = (const float4*)(envL + (size_t)k * 2097152);
        uint2* out = (uint2*)(envLh + (size_t)k * 2097152);
        const int flat = blockIdx.y * 128 + blockIdx.x;      // 0..2047
        const int i = flat * 256 + ty * 32 + tx;             // 0..524287
        const float4 v = in[i];
        union { unsigned short s[4]; uint2 d; } o;
        o.s[0] = f2h(v.x); o.s[1] = f2h(v.y); o.s[2] = f2h(v.z); o.s[3] = f2h(v.w);
        out[i] = o.d;
    }
}

__global__ void build_ops(const float* __restrict__ theta, float* __restrict__ ops)
{
    __shared__ float X[32][32], Pm[32][32];
    int i = threadIdx.y, j = threadIdx.x;
    float c = cosf(theta[0]), s = sinf(theta[0]);
    float aij = (j == i + 1) ? sqrtf((float)j) : 0.f;
    float aji = (i == j + 1) ? sqrtf((float)i) : 0.f;
    const float inv = 0.70710678118654752440f;
    float x0 = (aij + aji) * inv;
    float p0 = (aij - aji) * inv;
    X[i][j] = c * x0 + s * p0;
    Pm[i][j] = -s * x0 + c * p0;
    __syncthreads();
    float xx = 0.f, pp = 0.f;
    #pragma unroll
    for (int m = 0; m < 32; ++m) {
        xx += X[i][m] * X[m][j];
        pp += Pm[i][m] * Pm[m][j];
    }
    ops[0 * 1024 + i * 32 + j] = (i == j) ? 1.f : 0.f;
    ops[1 * 1024 + i * 32 + j] = X[i][j];
    ops[2 * 1024 + i * 32 + j] = Pm[i][j];
    ops[3 * 1024 + i * 32 + j] = xx;
    ops[4 * 1024 + i * 32 + j] = pp;
}

// W2p[k][(v*32+P)*256 + (w*32+p)] = pref[k] * sum_c coeffs[k,w,v,c] * ops[c][P,p]
__global__ void build_w(const float* __restrict__ coeffs, const float* __restrict__ ops,
                        const float* __restrict__ pref, float* __restrict__ W2)
{
    int b = blockIdx.x;  // (k,w,v)
    int k = b >> 6, w = (b >> 3) & 7, v = b & 7;
    int P = threadIdx.y, p = threadIdx.x;
    const float* cf = coeffs + ((k * 8 + w) * 8 + v) * 5;
    float acc = 0.f;
    #pragma unroll
    for (int c = 0; c < 5; ++c) acc += cf[c] * ops[c * 1024 + P * 32 + p];
    W2[(size_t)k * 65536 + (v * 32 + P) * 256 + (w * 32 + p)] = acc * pref[k];
}

__global__ void finalize_kernel(const float* __restrict__ dacc, const float* __restrict__ sumsq,
                                float* __restrict__ out)
{
    if (threadIdx.x == 0) out[0] = dacc[0] / sumsq[0];
}

extern "C" void kernel_launch(void* const* d_in, const int* in_sizes, int n_in,
                              void* d_out, int out_size, void* d_ws, size_t ws_size,
                              hipStream_t stream)
{
    const float* A      = (const float*)d_in[0];  // [512,32,512]
    const float* theta  = (const float*)d_in[1];
    const float* envL   = (const float*)d_in[2];  // [4,512,8,512]
    const float* envR   = (const float*)d_in[3];  // [4,512,8,512]
    const float* coeffs = (const float*)d_in[4];  // [4,8,8,5]
    const float* pref   = (const float*)d_in[5];  // [4]
    float* out = (float*)d_out;

    char* ws = (char*)d_ws;
    float* sumsq = (float*)ws;                                 // 4 B
    float* dacc  = (float*)(ws + 4);                           // 4 B
    float* ops   = (float*)(ws + 64);                          // 20 KB
    float* W2    = (float*)(ws + (32 << 10));                  // 1 MB
    unsigned short* envLh  = (unsigned short*)(ws + (4ull << 20));   // 16.8 MB
    unsigned short* Ah     = (unsigned short*)(ws + (21ull << 20));  // 16.8 MB
    unsigned short* Ath    = (unsigned short*)(ws + (38ull << 20));  // 16.8 MB
    unsigned short* envRth = (unsigned short*)(ws + (55ull << 20));  // 16.8 MB
    const size_t big0 = 72ull << 20;

    int Lt = 64;  // proven regime (ws < 328 MB per r10 WRITE_SIZE evidence)
    while (Lt > 16) {
        size_t need = big0 + 2ull * (size_t)Lt * (1ull << 20);  // T1 + Yp bytes
        if (need <= ws_size) break;
        Lt >>= 1;
    }
    unsigned short* T1 = (unsigned short*)(ws + big0);               // [4][Lt*8][16384]
    unsigned short* Yp = T1 + (size_t)Lt * 524288;                   // [Lt*32][16384]

    const int Lt8 = Lt * 8;
    const int kshiftA = __builtin_ctz(Lt8);                          // G1 k-slab shift
    const long long kextraA = 2097152LL - (long long)Lt8 * 512;
    const int NPB = Lt / 16;                                         // 256-row panels / block
    const int KT = Lt * 512;
    const int BKC = 512;
    const int zk = KT / BKC;
    const int zkShift = __builtin_ctz(zk);

    hipMemsetAsync(ws, 0, 64, stream);

    a_prep<<<dim3(512, 16), dim3(32, 8), 0, stream>>>(A, Ah, Ath, sumsq);
    env_prep<<<dim3(128, 16, 8), dim3(32, 8), 0, stream>>>(envL, envR, envLh, envRth);
    build_ops<<<1, dim3(32, 32), 0, stream>>>(theta, ops);
    build_w<<<256, dim3(32, 32), 0, stream>>>(coeffs, ops, pref, W2);

    const int ntiles = 512 / Lt;
    for (int t = 0; t < ntiles; ++t) {
        GArg g0, g1;
        // G1: T1[(k,lt,w)][(p,r)] = envL(tile,all k) x Ath^T  [M=4*Lt8, N=16384, K=512]
        g0.A = envLh + (size_t)t * Lt8 * 512; g0.B = Ath; g0.C = T1;
        g0.kshift = kshiftA; g0.kextra = kextraA;
        // G3: Y'[(lt,P)][(k,v,r)] = A(tile) x envRth^T        [M=Lt*32, N=16384, K=512]
        g1.A = Ah + (size_t)t * Lt * 16384; g1.B = envRth; g1.C = Yp;
        g1.kshift = 30; g1.kextra = 0;
        gemm_dual_mega<<<dim3(64, 2, 2), 512, 0, stream>>>(512, NPB, g0, g1);
        // G4: fused-trace contraction over (lt,r), all k
        gemm_g4w<<<dim3(4 * zk), 512, 0, stream>>>(T1, Yp, W2, dacc, Lt8, zkShift, BKC);
    }
    finalize_kernel<<<1, 64, 0, stream>>>(dacc, sumsq, out);
}

// Round 15
// 1021.967 us; speedup vs baseline: 1.0524x; 1.0524x over previous
//
#include <hip/hip_runtime.h>

// SingleSiteMinimizer, fp16-MFMA pipeline:
//   G1: T1[k][(L,w)][(p,r)] = envL_k @ A            } merged dual-grid dispatch
//   G3: Y'[(L,P)][k*4096+(v,r)] = A @ envR_k^T      } (blockIdx.z)
//   G4: out += sum_k sum_{m,n} (T1_k Y'_k^T)[m,n] * W2pref[k][n][m]  (fused trace)
//   out /= sum(A^2)
// Round 15: r12 GEMM config (measured best: mega 89us, g4w BKC=512) + rebuilt
// transposes: 64x64 tiles, float4 loads (256B/16-lane), uint2 transposed writes
// (128B/16-lane), LDS [64][65] 2-way-free column gather. r14's fused a_prep was
// latency-bound at 0.47 TB/s -> reverted.

typedef __attribute__((ext_vector_type(8))) _Float16 f16x8;
typedef __attribute__((ext_vector_type(4))) float f32x4;

#define RPS 280  // repack LDS row stride in shorts (140 dw: rows {0,4,8,12} -> 2-way)

__device__ __forceinline__ unsigned short f2h(float f) {
    _Float16 h = (_Float16)f;
    return *(unsigned short*)&h;
}

__device__ __forceinline__ void gload16(const void* g, void* l) {
    __builtin_amdgcn_global_load_lds(
        (const __attribute__((address_space(1))) void*)g,
        (__attribute__((address_space(3))) void*)l, 16, 0, 0);
}

struct GArg {
    const unsigned short* A;
    const unsigned short* B;
    unsigned short* C;
    int kshift;        // A row slab shift (30 => none)
    long long kextra;  // extra elems per slab
};

// Stage one 256x64 fp16 K-tile of A and B into linear LDS with inverse-swizzled
// global source: LDS slot (r, s) holds global k-chunk s^(r&7)  [rule 21].
__device__ __forceinline__ void stage_tile(
    const GArg& g, int srow0, int col0, int kt0,
    short* dstA, short* dstB, int tid)
{
    #pragma unroll
    for (int q = 0; q < 4; ++q) {
        const int c = q * 512 + tid;
        const int r = c >> 3;
        const int gs = (c & 7) ^ (r & 7);
        const int gr = srow0 + r;
        const size_t aoff = (size_t)gr * 512 + (size_t)((unsigned)gr >> g.kshift) * g.kextra;
        gload16(g.A + aoff + kt0 + gs * 8, dstA + c * 8);
        gload16(g.B + (size_t)(col0 + r) * 512 + kt0 + gs * 8, dstB + c * 8);
    }
}

// ---------- mega dual fp16 GEMM: C[M,N] = Aop[M,K] x Bop[N,K]^T ----------
// K=512. lda=ldb=512, ldc=16384. grid (64, 2, 2); NPB 256-row panels per block.
__global__ __launch_bounds__(512, 1) void gemm_dual_mega(int K, int NPB, GArg g0, GArg g1)
{
    __shared__ short lds[74496];  // 128KB staging (A0,B0,A1,B1) + 17.5KB repack
    const GArg g = blockIdx.z ? g1 : g0;
    const int tid = threadIdx.x;
    const int wid = tid >> 6, lane = tid & 63;
    const int wm = wid >> 2, wn = wid & 3;          // 2M x 4N waves
    const int lrow = lane & 15, lgrp = lane >> 4;
    const int sx = lrow & 7;                        // read-side swizzle xor
    const int gsw0 = (lgrp ^ sx) * 8, gsw1 = ((lgrp + 4) ^ sx) * 8;

    // XCD pin: hw linear id % 8 == blockIdx.x % 8 for this grid shape
    const int xcd = blockIdx.x & 7, loc = blockIdx.x >> 3;
    const int col0 = (xcd * 8 + loc) * 256;
    const int row_base = blockIdx.y * NPB * 256;

    short* A0 = lds;          short* B0 = lds + 16384;
    short* A1 = lds + 32768;  short* B1 = lds + 49152;
    short* repk = lds + 65536;                       // 32 x RPS shorts

    const int NT = (K >> 6) * NPB;                   // flat iterations

    f32x4 acc[8][4] = {};

    // prologue: stage it=0,1
    stage_tile(g, row_base, col0, 0, A0, B0, tid);
    stage_tile(g, row_base, col0, 64, A1, B1, tid);
    asm volatile("s_waitcnt vmcnt(8)" ::: "memory");
    __builtin_amdgcn_s_barrier();
    __builtin_amdgcn_sched_barrier(0);

    for (int it = 0; it < NT; ++it) {
        const short* cA = (it & 1) ? A1 : A0;
        const short* cB = (it & 1) ? B1 : B0;
        short* wA = (it & 1) ? A1 : A0;
        short* wB = (it & 1) ? B1 : B0;

        f16x8 bfr[4][2], afr[4][2];
        #pragma unroll
        for (int j = 0; j < 4; ++j) {
            const int R = wn * 64 + j * 16 + lrow;
            bfr[j][0] = *(const f16x8*)&cB[R * 64 + gsw0];
            bfr[j][1] = *(const f16x8*)&cB[R * 64 + gsw1];
        }
        #pragma unroll
        for (int i = 0; i < 4; ++i) {
            const int R = wm * 128 + i * 16 + lrow;
            afr[i][0] = *(const f16x8*)&cA[R * 64 + gsw0];
            afr[i][1] = *(const f16x8*)&cA[R * 64 + gsw1];
        }
        __builtin_amdgcn_s_setprio(1);
        #pragma unroll
        for (int i = 0; i < 4; ++i)
            #pragma unroll
            for (int j = 0; j < 4; ++j) {
                acc[i][j] = __builtin_amdgcn_mfma_f32_16x16x32_f16(afr[i][0], bfr[j][0], acc[i][j], 0, 0, 0);
                acc[i][j] = __builtin_amdgcn_mfma_f32_16x16x32_f16(afr[i][1], bfr[j][1], acc[i][j], 0, 0, 0);
            }
        __builtin_amdgcn_s_setprio(0);
        // phase-2 A fragments (rows 64..127 of the wave's M-half)
        #pragma unroll
        for (int i = 0; i < 4; ++i) {
            const int R = wm * 128 + (i + 4) * 16 + lrow;
            afr[i][0] = *(const f16x8*)&cA[R * 64 + gsw0];
            afr[i][1] = *(const f16x8*)&cA[R * 64 + gsw1];
        }
        asm volatile("s_waitcnt lgkmcnt(0)" ::: "memory");
        __builtin_amdgcn_sched_barrier(0);
        __builtin_amdgcn_s_barrier();               // all reads of buf[it&1] retired
        __builtin_amdgcn_sched_barrier(0);
        if (it + 2 < NT) {
            const int it2 = it + 2;
            stage_tile(g, row_base + (it2 >> 3) * 256, col0, (it2 & 7) * 64, wA, wB, tid);
        }
        __builtin_amdgcn_s_setprio(1);
        #pragma unroll
        for (int i = 0; i < 4; ++i)
            #pragma unroll
            for (int j = 0; j < 4; ++j) {
                acc[i + 4][j] = __builtin_amdgcn_mfma_f32_16x16x32_f16(afr[i][0], bfr[j][0], acc[i + 4][j], 0, 0, 0);
                acc[i + 4][j] = __builtin_amdgcn_mfma_f32_16x16x32_f16(afr[i][1], bfr[j][1], acc[i + 4][j], 0, 0, 0);
            }
        __builtin_amdgcn_s_setprio(0);
        __builtin_amdgcn_sched_barrier(0);
        if (it + 2 < NT) asm volatile("s_waitcnt vmcnt(8)" ::: "memory");  // it+1 landed
        else             asm volatile("s_waitcnt vmcnt(0)" ::: "memory");  // tail drain
        __builtin_amdgcn_sched_barrier(0);
        __builtin_amdgcn_s_barrier();
        __builtin_amdgcn_sched_barrier(0);

        // ---- panel boundary: write this panel's C, reset acc. Raw barriers only
        // (no __syncthreads: must not drain the in-flight cross-panel prefetch).
        if ((it & 7) == 7) {
            const int row0 = row_base + (it >> 3) * 256;
            const int orow = lgrp * 4, ocol = lrow;
            #pragma unroll
            for (int c8 = 0; c8 < 8; ++c8) {        // 32-row chunks
                if (wm == (c8 >> 2)) {
                    const int ib = (c8 & 3) * 2;
                    #pragma unroll
                    for (int di = 0; di < 2; ++di)
                        #pragma unroll
                        for (int j = 0; j < 4; ++j)
                            #pragma unroll
                            for (int q = 0; q < 4; ++q)
                                repk[(di * 16 + orow + q) * RPS + wn * 64 + j * 16 + ocol] =
                                    (short)f2h(acc[ib + di][j][q]);
                }
                asm volatile("s_waitcnt lgkmcnt(0)" ::: "memory");
                __builtin_amdgcn_s_barrier();
                #pragma unroll
                for (int s2 = 0; s2 < 2; ++s2) {
                    const int idx = s2 * 512 + tid;
                    const int rr = idx >> 5, cc = idx & 31;
                    *(int4*)(g.C + (size_t)(row0 + c8 * 32 + rr) * 16384 + col0 + cc * 8) =
                        *(const int4*)&repk[rr * RPS + cc * 8];
                }
                asm volatile("s_waitcnt lgkmcnt(0)" ::: "memory");
                __builtin_amdgcn_s_barrier();
            }
            #pragma unroll
            for (int i = 0; i < 8; ++i)
                #pragma unroll
                for (int j = 0; j < 4; ++j)
                    acc[i][j] = (f32x4){0.f, 0.f, 0.f, 0.f};
        }
    }
}

// ---------- G4: 512-thr, 8 waves 2Mx4N (128x64/wave), full 256x256 per block ----------
__global__ __launch_bounds__(512, 1) void gemm_g4w(
    const unsigned short* __restrict__ T1, const unsigned short* __restrict__ Yp,
    const float* __restrict__ W2p, float* __restrict__ dacc,
    int Lt8, int zkShift, int BKC)
{
    __shared__ short sh[16384];  // A = sh[0:8192] [256][32], B = sh[8192:16384]
    const int tid = threadIdx.x;
    const int wid = tid >> 6, lane = tid & 63;
    const int kidx = blockIdx.x >> zkShift;
    const int kz = (blockIdx.x - (kidx << zkShift)) * BKC;
    const int wm = wid >> 2, wn = wid & 3;          // 2M x 4N waves
    const int lrow = lane & 15, lgrp = lane >> 4;
    const int rdoff = lrow * 32 + ((lgrp ^ ((lrow >> 1) & 3)) * 8);

    const size_t T1k = (size_t)kidx * Lt8 * 16384;
    const size_t Yk = (size_t)kidx * 4096;

    f32x4 acc[8][4] = {};

    for (int k0 = 0; k0 < BKC; k0 += 32) {
        const int kk = kz + k0;
        const int lt = kk >> 9, rbase = kk & 511;
        #pragma unroll
        for (int q = 0; q < 2; ++q) {
            const int c = q * 512 + tid;
            const int row = c >> 2;
            const int gs = (c & 3) ^ ((row >> 1) & 3);
            const int hi = row >> 5, lo = row & 31;
            gload16(T1 + T1k + (size_t)(lt * 8 + hi) * 16384 + lo * 512 + rbase + gs * 8,
                    sh + c * 8);
            gload16(Yp + Yk + (size_t)(lt * 32 + lo) * 16384 + hi * 512 + rbase + gs * 8,
                    sh + 8192 + c * 8);
        }
        __syncthreads();
        f16x8 a[8], b[4];
        #pragma unroll
        for (int j = 0; j < 4; ++j)
            b[j] = *(const f16x8*)&sh[8192 + (wn * 64 + j * 16) * 32 + rdoff];
        #pragma unroll
        for (int i = 0; i < 8; ++i)
            a[i] = *(const f16x8*)&sh[(wm * 128 + i * 16) * 32 + rdoff];
        #pragma unroll
        for (int i = 0; i < 8; ++i)
            #pragma unroll
            for (int j = 0; j < 4; ++j)
                acc[i][j] = __builtin_amdgcn_mfma_f32_16x16x32_f16(a[i], b[j], acc[i][j], 0, 0, 0);
        __syncthreads();
    }

    // fused weighted trace: s = sum acc[i][j][q] * Wk[n*256 + m]
    const int orow = lgrp * 4, ocol = lrow;
    const float* Wk = W2p + ((size_t)kidx << 16);
    float s = 0.f;
    #pragma unroll
    for (int j = 0; j < 4; ++j) {
        const int n = wn * 64 + j * 16 + ocol;
        const float* wrow = Wk + (size_t)n * 256 + wm * 128 + orow;
        #pragma unroll
        for (int i = 0; i < 8; ++i) {
            float4 wv = *(const float4*)(wrow + i * 16);
            s += wv.x * acc[i][j][0] + wv.y * acc[i][j][1]
               + wv.z * acc[i][j][2] + wv.w * acc[i][j][3];
        }
    }
    __syncthreads();
    float* red = (float*)sh;
    red[tid] = s;
    __syncthreads();
    for (int st = 256; st > 0; st >>= 1) {
        if (tid < st) red[tid] += red[tid + st];
        __syncthreads();
    }
    if (tid == 0) atomicAdd(dacc, red[0]);
}

// ---------- prep kernels ----------
__global__ __launch_bounds__(256) void cast_sumsq(
    const float* __restrict__ in, unsigned short* __restrict__ out,
    long long n4, float* __restrict__ sumsq)
{
    float p = 0.f;
    for (long long i = (long long)blockIdx.x * blockDim.x + threadIdx.x; i < n4;
         i += (long long)gridDim.x * blockDim.x) {
        float4 v = ((const float4*)in)[i];
        p += v.x * v.x + v.y * v.y + v.z * v.z + v.w * v.w;
        union { unsigned short s[4]; uint2 d; } o;
        o.s[0] = f2h(v.x); o.s[1] = f2h(v.y); o.s[2] = f2h(v.z); o.s[3] = f2h(v.w);
        ((uint2*)out)[i] = o.d;
    }
    __shared__ float sh[256];
    sh[threadIdx.x] = p;
    __syncthreads();
    for (int s = 128; s > 0; s >>= 1) {
        if (threadIdx.x < s) sh[threadIdx.x] += sh[threadIdx.x + s];
        __syncthreads();
    }
    if (threadIdx.x == 0) atomicAdd(sumsq, sh[0]);
}

__global__ void cast_kernel(const float* __restrict__ in, unsigned short* __restrict__ out,
                            long long n4)
{
    for (long long i = (long long)blockIdx.x * blockDim.x + threadIdx.x; i < n4;
         i += (long long)gridDim.x * blockDim.x) {
        float4 v = ((const float4*)in)[i];
        union { unsigned short s[4]; uint2 d; } o;
        o.s[0] = f2h(v.x); o.s[1] = f2h(v.y); o.s[2] = f2h(v.z); o.s[3] = f2h(v.w);
        ((uint2*)out)[i] = o.d;
    }
}

// transpose-cast f32 [R_in rows][C cols] -> f16 [C][R_in], 64x64 tiles.
// float4 loads (16 lanes x 16B = 256B), uint2 transposed writes (16 x 8B = 128B).
// grid (C/64, R_in/64, Z), block 256.
__global__ void transpose_cast4(const float* __restrict__ in, unsigned short* __restrict__ out,
                                int R, int C, long long in_stride, long long out_stride)
{
    __shared__ float tile[64][65];
    in += (long long)blockIdx.z * in_stride;
    out += (long long)blockIdx.z * out_stride;
    const int c0 = blockIdx.x * 64, r0 = blockIdx.y * 64;
    const int t = threadIdx.x;
    const int lr = t >> 4, lf = t & 15;
    #pragma unroll
    for (int i = 0; i < 4; ++i) {
        const int rr = i * 16 + lr;
        float4 v = *(const float4*)(in + (size_t)(r0 + rr) * C + c0 + lf * 4);
        tile[rr][lf * 4 + 0] = v.x;
        tile[rr][lf * 4 + 1] = v.y;
        tile[rr][lf * 4 + 2] = v.z;
        tile[rr][lf * 4 + 3] = v.w;
    }
    __syncthreads();
    #pragma unroll
    for (int i = 0; i < 4; ++i) {
        const int orow = i * 16 + lr;       // output row = source column index
        const int seg = lf;                 // 4-short segment along source rows
        union { unsigned short s[4]; uint2 d; } o;
        #pragma unroll
        for (int q = 0; q < 4; ++q)
            o.s[q] = f2h(tile[seg * 4 + q][orow]);
        *(uint2*)(out + (size_t)(c0 + orow) * R + r0 + seg * 4) = o.d;
    }
}

__global__ void build_ops(const float* __restrict__ theta, float* __restrict__ ops)
{
    __shared__ float X[32][32], Pm[32][32];
    int i = threadIdx.y, j = threadIdx.x;
    float c = cosf(theta[0]), s = sinf(theta[0]);
    float aij = (j == i + 1) ? sqrtf((float)j) : 0.f;
    float aji = (i == j + 1) ? sqrtf((float)i) : 0.f;
    const float inv = 0.70710678118654752440f;
    float x0 = (aij + aji) * inv;
    float p0 = (aij - aji) * inv;
    X[i][j] = c * x0 + s * p0;
    Pm[i][j] = -s * x0 + c * p0;
    __syncthreads();
    float xx = 0.f, pp = 0.f;
    #pragma unroll
    for (int m = 0; m < 32; ++m) {
        xx += X[i][m] * X[m][j];
        pp += Pm[i][m] * Pm[m][j];
    }
    ops[0 * 1024 + i * 32 + j] = (i == j) ? 1.f : 0.f;
    ops[1 * 1024 + i * 32 + j] = X[i][j];
    ops[2 * 1024 + i * 32 + j] = Pm[i][j];
    ops[3 * 1024 + i * 32 + j] = xx;
    ops[4 * 1024 + i * 32 + j] = pp;
}

// W2p[k][(v*32+P)*256 + (w*32+p)] = pref[k] * sum_c coeffs[k,w,v,c] * ops[c][P,p]
__global__ void build_w(const float* __restrict__ coeffs, const float* __restrict__ ops,
                        const float* __restrict__ pref, float* __restrict__ W2)
{
    int b = blockIdx.x;  // (k,w,v)
    int k = b >> 6, w = (b >> 3) & 7, v = b & 7;
    int P = threadIdx.y, p = threadIdx.x;
    const float* cf = coeffs + ((k * 8 + w) * 8 + v) * 5;
    float acc = 0.f;
    #pragma unroll
    for (int c = 0; c < 5; ++c) acc += cf[c] * ops[c * 1024 + P * 32 + p];
    W2[(size_t)k * 65536 + (v * 32 + P) * 256 + (w * 32 + p)] = acc * pref[k];
}

__global__ void finalize_kernel(const float* __restrict__ dacc, const float* __restrict__ sumsq,
                                float* __restrict__ out)
{
    if (threadIdx.x == 0) out[0] = dacc[0] / sumsq[0];
}

extern "C" void kernel_launch(void* const* d_in, const int* in_sizes, int n_in,
                              void* d_out, int out_size, void* d_ws, size_t ws_size,
                              hipStream_t stream)
{
    const float* A      = (const float*)d_in[0];  // [512,32,512]
    const float* theta  = (const float*)d_in[1];
    const float* envL   = (const float*)d_in[2];  // [4,512,8,512]
    const float* envR   = (const float*)d_in[3];  // [4,512,8,512]
    const float* coeffs = (const float*)d_in[4];  // [4,8,8,5]
    const float* pref   = (const float*)d_in[5];  // [4]
    float* out = (float*)d_out;

    char* ws = (char*)d_ws;
    float* sumsq = (float*)ws;                                 // 4 B
    float* dacc  = (float*)(ws + 4);                           // 4 B
    float* ops   = (float*)(ws + 64);                          // 20 KB
    float* W2    = (float*)(ws + (32 << 10));                  // 1 MB
    unsigned short* envLh  = (unsigned short*)(ws + (4ull << 20));   // 16.8 MB
    unsigned short* Ah     = (unsigned short*)(ws + (21ull << 20));  // 16.8 MB
    unsigned short* Ath    = (unsigned short*)(ws + (38ull << 20));  // 16.8 MB
    unsigned short* envRth = (unsigned short*)(ws + (55ull << 20));  // 16.8 MB
    const size_t big0 = 72ull << 20;

    int Lt = 64;  // proven regime
    while (Lt > 16) {
        size_t need = big0 + 2ull * (size_t)Lt * (1ull << 20);  // T1 + Yp bytes
        if (need <= ws_size) break;
        Lt >>= 1;
    }
    unsigned short* T1 = (unsigned short*)(ws + big0);               // [4][Lt*8][16384]
    unsigned short* Yp = T1 + (size_t)Lt * 524288;                   // [Lt*32][16384]

    const int Lt8 = Lt * 8;
    const int kshiftA = __builtin_ctz(Lt8);                          // G1 k-slab shift
    const long long kextraA = 2097152LL - (long long)Lt8 * 512;
    const int NPB = Lt / 16;                                         // 256-row panels / block
    const int KT = Lt * 512;
    const int BKC = 512;
    const int zk = KT / BKC;
    const int zkShift = __builtin_ctz(zk);

    hipMemsetAsync(ws, 0, 64, stream);

    cast_sumsq<<<1024, 256, 0, stream>>>(A, Ah, 2097152LL, sumsq);
    cast_kernel<<<2048, 256, 0, stream>>>(envL, envLh, 2097152LL);
    transpose_cast4<<<dim3(256, 8, 1), 256, 0, stream>>>(A, Ath, 512, 16384, 0, 0);
    transpose_cast4<<<dim3(64, 8, 4), 256, 0, stream>>>(envR, envRth, 512, 4096,
                                                        2097152LL, 2097152LL);
    build_ops<<<1, dim3(32, 32), 0, stream>>>(theta, ops);
    build_w<<<256, dim3(32, 32), 0, stream>>>(coeffs, ops, pref, W2);

    const int ntiles = 512 / Lt;
    for (int t = 0; t < ntiles; ++t) {
        GArg g0, g1;
        // G1: T1[(k,lt,w)][(p,r)] = envL(tile,all k) x Ath^T  [M=4*Lt8, N=16384, K=512]
        g0.A = envLh + (size_t)t * Lt8 * 512; g0.B = Ath; g0.C = T1;
        g0.kshift = kshiftA; g0.kextra = kextraA;
        // G3: Y'[(lt,P)][(k,v,r)] = A(tile) x envRth^T        [M=Lt*32, N=16384, K=512]
        g1.A = Ah + (size_t)t * Lt * 16384; g1.B = envRth; g1.C = Yp;
        g1.kshift = 30; g1.kextra = 0;
        gemm_dual_mega<<<dim3(64, 2, 2), 512, 0, stream>>>(512, NPB, g0, g1);
        // G4: fused-trace contraction over (lt,r), all k
        gemm_g4w<<<dim3(4 * zk), 512, 0, stream>>>(T1, Yp, W2, dacc, Lt8, zkShift, BKC);
    }
    finalize_kernel<<<1, 64, 0, stream>>>(dacc, sumsq, out);
}